// Round 7
// baseline (2544.640 us; speedup 1.0000x reference)
//
#include <hip/hip_runtime.h>
#include <stdint.h>

#define B_ 8
#define D_ 128
#define T_ 4096
#define Q_ 30
#define C_ 1024

typedef __attribute__((ext_vector_type(8))) _Float16 half8;
typedef __attribute__((ext_vector_type(4))) float float4_;
typedef __attribute__((ext_vector_type(2))) float float2_;

// row-major fp16 codebook image [Q*C][128] — B-fragments load straight from here.
__device__ __align__(16) _Float16 g_half[(size_t)Q_*C_*D_];

// ---------------- prep 1: per-code ||c||^2, fp64 accumulation ----------------
__global__ void rvq_prep(const float* __restrict__ cb, float* __restrict__ sumsq){
  int g    = blockIdx.x*128 + (threadIdx.x>>1);
  int half = threadIdx.x & 1;
  const float* src = cb + (size_t)g*D_ + half*64;
  double s = 0.0;
#pragma unroll
  for (int i=0;i<64;i+=4){
    float4_ f = *(const float4_*)(src+i);
    s += (double)f.x*f.x + (double)f.y*f.y + (double)f.z*f.z + (double)f.w*f.w;
  }
  s += __shfl_xor(s, 1);
  if (!half) sumsq[g] = (float)s;
}

// ---------------- prep 2: fp32 -> fp16 codebook, row-major -------------------
__global__ void rvq_h(const float* __restrict__ cb){
  const size_t i = ((size_t)blockIdx.x*256 + threadIdx.x)*8;
  float4_ f0 = *(const float4_*)(cb + i);
  float4_ f1 = *(const float4_*)(cb + i + 4);
  half8 h;
  h[0]=(_Float16)f0.x; h[1]=(_Float16)f0.y; h[2]=(_Float16)f0.z; h[3]=(_Float16)f0.w;
  h[4]=(_Float16)f1.x; h[5]=(_Float16)f1.y; h[6]=(_Float16)f1.z; h[7]=(_Float16)f1.w;
  *(half8*)(g_half + i) = h;
}

// --- main: 30-step RVQ, 32 rows/wave, 256 blocks (R0 structure, verified 1562us).
// Hard-won constraints (R1-R6):
//  - fp64 residual chain is semantically required (R3).
//  - 32 rows/wave => 1024 waves = 1 wave/SIMD, grid-limited; all 16-row
//    2-wave variants lost (R1/R2/R4/R5) — per-wave tail cost doubles.
//  - 256 arch VGPRs is a hard PER-WAVE cap: the 4-candidate-parallel fp64
//    rescore needs ~300 live regs and spills GBs to scratch at ANY occupancy
//    (R5: 75MB, R6: 3.7GB WRITE_SIZE). Rescore must stay sequential.
// Kept from R6 (register-cheap, validated):
//  - branch-free top-2 insert: med3 + min (2 ops vs ~5)
//  - branch-free top-4 scan: min + 3x med3 over float4 LDS reads, full 10-bit
//    code id packed in score mantissa (perturbation 2^-13 rel << fp16 score
//    noise; fp64 rescore decides the final winner exactly)
__global__ __launch_bounds__(256) void rvq_main(
    const float* __restrict__ x, const float* __restrict__ cb,
    const float* __restrict__ sumsq, double* __restrict__ lossAcc,
    float* __restrict__ out)
{
  __shared__ float sCS[4][32][36];   // per-wave packed top2 scores (stride 36 = 16B-aligned rows)
  __shared__ int   sI4[4][32][4];    // per-row top-4 global code ids

  const int tid  = threadIdx.x;
  const int wv   = tid>>6;
  const int ln   = tid&63;
  const int col  = ln&15;
  const int quad = ln>>4;
  const int blk  = blockIdx.x;
  const int b    = blk>>5;
  const int t0   = ((blk&31)<<7) + (wv<<5);

  // residual fp64, A-frag distribution: row = rt*16+col, dim = kc*32+quad*8+j
  double rmast[2][4][8];
#pragma unroll
  for (int rt=0;rt<2;++rt){
    const int t = t0 + rt*16 + col;
#pragma unroll
    for (int kc=0;kc<4;++kc)
#pragma unroll
      for (int j=0;j<8;++j){
        const int d = kc*32 + quad*8 + j;
        rmast[rt][kc][j] = (double)x[((size_t)b*D_ + d)*T_ + t];
      }
  }

  half8 ah[2][4];
  auto makeAB = [&](){
#pragma unroll
    for (int rt=0;rt<2;++rt)
#pragma unroll
      for (int kc=0;kc<4;++kc){
        half8 h;
#pragma unroll
        for (int j=0;j<8;++j) h[j] = (_Float16)(float)rmast[rt][kc][j];
        ah[rt][kc] = h;
      }
  };
  makeAB();

  double lossd = 0.0;

  // register pipeline buffers: B-fragments + cc for one group (32 codes)
  half8 bufA[8], bufB[8];
  float ccA[2],  ccB[2];

  const _Float16* cbh0 = g_half;
  const float*    ssq0 = sumsq;

  auto loadGroup = [&](const _Float16* cbh, const float* ssq, int g, half8* Bv, float* cc){
#pragma unroll
    for (int kc=0;kc<4;++kc)
#pragma unroll
      for (int ct=0;ct<2;++ct){
        const int n = g*32 + ct*16 + col;
        Bv[kc*2+ct] = *(const half8*)(cbh + n*128 + kc*32 + quad*8);
      }
#pragma unroll
    for (int ct=0;ct<2;++ct)
      cc[ct] = ssq[(g*2+ct)*16 + col];
  };

  loadGroup(cbh0, ssq0, 0, bufA, ccA);   // prologue: q=0, group 0

  for (int q=0;q<Q_;++q){
    const float*    cbq = cb    + (size_t)q*C_*D_;
    const _Float16* cbh = g_half + (size_t)q*C_*D_;
    const float*    ssq = sumsq + q*C_;

    // packed top-2 per cell: score float with low 10 mantissa bits = full code id
    float p1[2][4], p2[2][4];
#pragma unroll
    for (int rt=0;rt<2;++rt)
#pragma unroll
      for (int rg=0;rg<4;++rg){ p1[rt][rg]=3.0e38f; p2[rt][rg]=3.0e38f; }

#pragma unroll
    for (int g=0; g<32; ++g){
      half8* cur = (g&1) ? bufB : bufA;
      float* ccc = (g&1) ? ccB  : ccA;
      // prefetch next group (codebook loads independent of residual —
      // cross-q prefetch of (q+1, group 0) overlaps the q-tail)
      if (g < 31){
        loadGroup(cbh, ssq, g+1, (g&1)?bufA:bufB, (g&1)?ccA:ccB);
      } else if (q+1 < Q_){
        loadGroup(cbh + C_*D_, ssq + C_, 0, (g&1)?bufA:bufB, (g&1)?ccA:ccB);
      }

      float4_ acc[2][2];
#pragma unroll
      for (int a=0;a<2;++a)
#pragma unroll
        for (int c2=0;c2<2;++c2) acc[a][c2] = (float4_){0.f,0.f,0.f,0.f};
#pragma unroll
      for (int kc=0;kc<4;++kc)
#pragma unroll
        for (int rt=0;rt<2;++rt)
#pragma unroll
          for (int ct=0;ct<2;++ct)
            acc[rt][ct] = __builtin_amdgcn_mfma_f32_16x16x32_f16(ah[rt][kc], cur[kc*2+ct], acc[rt][ct], 0,0,0);

#pragma unroll
      for (int ct=0;ct<2;++ct){
        // full 10-bit code id = (g*2+ct)*16 + col; high 6 bits compile-time
        const unsigned idc = ((unsigned)(g*2+ct))<<4;
#pragma unroll
        for (int rt=0;rt<2;++rt)
#pragma unroll
          for (int rg=0;rg<4;++rg){
            float sc = fmaf(-2.0f, acc[rt][ct][rg], ccc[ct]);
            unsigned u = (__builtin_bit_cast(unsigned, sc) & ~1023u) | idc | (unsigned)col;
            float sp = __builtin_bit_cast(float, u);
            // branch-free sorted-pair insert
            p2[rt][rg] = __builtin_amdgcn_fmed3f(sp, p1[rt][rg], p2[rt][rg]);
            p1[rt][rg] = fminf(sp, p1[rt][rg]);
          }
      }
    }

    // ---- publish per-lane packed top-2 (wave-private, lockstep) ----
#pragma unroll
    for (int rt=0;rt<2;++rt)
#pragma unroll
      for (int rg=0;rg<4;++rg){
        const int row = rt*16 + quad*4 + rg;
        *(float2_*)&sCS[wv][row][col*2] = (float2_){p1[rt][rg], p2[rt][rg]};
      }

    // ---- lanes 0..31: branch-free top-4 of own row's 32 packed entries ----
    if (ln < 32){
      const int row = ln;
      float b0=3.0e38f,b1=3.0e38f,b2=3.0e38f,b3=3.0e38f;
#pragma unroll
      for (int i=0;i<8;++i){
        float4_ v = *(const float4_*)&sCS[wv][row][i*4];
#pragma unroll
        for (int k2=0;k2<4;++k2){
          const float sc = v[k2];
          // sorted insert into (b0<=b1<=b2<=b3), ids ride in low bits
          b3 = __builtin_amdgcn_fmed3f(sc, b2, b3);
          b2 = __builtin_amdgcn_fmed3f(sc, b1, b2);
          b1 = __builtin_amdgcn_fmed3f(sc, b0, b1);
          b0 = fminf(sc, b0);
        }
      }
      sI4[wv][row][0] = (int)(__builtin_bit_cast(unsigned, b0) & 1023u);
      sI4[wv][row][1] = (int)(__builtin_bit_cast(unsigned, b1) & 1023u);
      sI4[wv][row][2] = (int)(__builtin_bit_cast(unsigned, b2) & 1023u);
      sI4[wv][row][3] = (int)(__builtin_bit_cast(unsigned, b3) & 1023u);
    }

    // ---- fp64 exact rescore of top-4, SEQUENTIAL (register-bounded) ---------
#pragma unroll
    for (int rt=0;rt<2;++rt){
      const int m = rt*16 + col;
      double bestS = 1.0e300; int bestJ = 0x7fffffff;
#pragma unroll
      for (int cnd=0;cnd<4;++cnd){
        const int jj = sI4[wv][m][cnd];
        const float* p = cbq + ((size_t)jj<<7) + (quad<<3);
        double sd = 0.0;
#pragma unroll
        for (int kc=0;kc<4;++kc){
          float4_ a0 = *(const float4_*)(p + kc*32);
          float4_ a1 = *(const float4_*)(p + kc*32 + 4);
          float fv[8] = {a0.x,a0.y,a0.z,a0.w,a1.x,a1.y,a1.z,a1.w};
#pragma unroll
          for (int j=0;j<8;++j){
            double cd = (double)fv[j];
            sd += cd*(cd - 2.0*rmast[rt][kc][j]);
          }
        }
        sd += __shfl_xor(sd, 16); sd += __shfl_xor(sd, 32);
        if ((sd < bestS) || (sd == bestS && jj < bestJ)){ bestS = sd; bestJ = jj; }
      }
      const float* pw = cbq + ((size_t)bestJ<<7) + (quad<<3);
#pragma unroll
      for (int kc=0;kc<4;++kc){
        float4_ w0 = *(const float4_*)(pw + kc*32);
        float4_ w1 = *(const float4_*)(pw + kc*32 + 4);
        float fw[8] = {w0.x,w0.y,w0.z,w0.w,w1.x,w1.y,w1.z,w1.w};
#pragma unroll
        for (int j=0;j<8;++j){
          double rn = rmast[rt][kc][j] - (double)fw[j];
          rmast[rt][kc][j] = rn;
          lossd += rn*rn;
        }
      }
    }
    makeAB();
  }

  // ---- epilogue: quantized = x - r_final ----
#pragma unroll
  for (int rt=0;rt<2;++rt){
    const int t = t0 + rt*16 + col;
#pragma unroll
    for (int kc=0;kc<4;++kc)
#pragma unroll
      for (int j=0;j<8;++j){
        const int d = kc*32 + quad*8 + j;
        const size_t o = ((size_t)b*D_ + d)*T_ + t;
        out[o] = (float)((double)x[o] - rmast[rt][kc][j]);
      }
  }
#pragma unroll
  for (int mk=1; mk<64; mk<<=1) lossd += __shfl_xor(lossd, mk);
  if (ln==0) atomicAdd(lossAcc, lossd);
}

__global__ void rvq_fin(const double* __restrict__ lossAcc, float* __restrict__ out){
  out[(size_t)B_*D_*T_] = (float)(*lossAcc * (1.0/((double)B_*(double)D_*(double)T_)));
}

extern "C" void kernel_launch(void* const* d_in, const int* in_sizes, int n_in,
                              void* d_out, int out_size, void* d_ws, size_t ws_size,
                              hipStream_t stream) {
  const float* x  = (const float*)d_in[0];   // [B, D, T] fp32
  const float* cb = (const float*)d_in[1];   // [Q, C, D] fp32
  float* out      = (float*)d_out;           // [B*D*T] quantized + [1] loss
  double* lossAcc = (double*)d_ws;
  float*  sumsq   = (float*)((char*)d_ws + 256);   // Q*C floats

  hipMemsetAsync(d_ws, 0, 256, stream);
  rvq_prep<<<Q_*C_/128, 256, 0, stream>>>(cb, sumsq);
  rvq_h   <<<(Q_*C_*D_)/(256*8), 256, 0, stream>>>(cb);
  rvq_main<<<(B_*T_)/128, 256, 0, stream>>>(x, cb, sumsq, lossAcc, out);
  rvq_fin <<<1, 1, 0, stream>>>(lossAcc, out);
}

// Round 8
// 2424.526 us; speedup vs baseline: 1.0495x; 1.0495x over previous
//
#include <hip/hip_runtime.h>
#include <stdint.h>

#define B_ 8
#define D_ 128
#define T_ 4096
#define Q_ 30
#define C_ 1024

typedef __attribute__((ext_vector_type(8))) _Float16 half8;
typedef __attribute__((ext_vector_type(4))) float float4_;

// row-major fp16 codebook image [Q*C][128] — B-fragments load straight from here.
__device__ __align__(16) _Float16 g_half[(size_t)Q_*C_*D_];

// ---------------- prep 1: per-code ||c||^2, fp64 accumulation ----------------
__global__ void rvq_prep(const float* __restrict__ cb, float* __restrict__ sumsq){
  int g    = blockIdx.x*128 + (threadIdx.x>>1);
  int half = threadIdx.x & 1;
  const float* src = cb + (size_t)g*D_ + half*64;
  double s = 0.0;
#pragma unroll
  for (int i=0;i<64;i+=4){
    float4_ f = *(const float4_*)(src+i);
    s += (double)f.x*f.x + (double)f.y*f.y + (double)f.z*f.z + (double)f.w*f.w;
  }
  s += __shfl_xor(s, 1);
  if (!half) sumsq[g] = (float)s;
}

// ---------------- prep 2: fp32 -> fp16 codebook, row-major -------------------
__global__ void rvq_h(const float* __restrict__ cb){
  const size_t i = ((size_t)blockIdx.x*256 + threadIdx.x)*8;
  float4_ f0 = *(const float4_*)(cb + i);
  float4_ f1 = *(const float4_*)(cb + i + 4);
  half8 h;
  h[0]=(_Float16)f0.x; h[1]=(_Float16)f0.y; h[2]=(_Float16)f0.z; h[3]=(_Float16)f0.w;
  h[4]=(_Float16)f1.x; h[5]=(_Float16)f1.y; h[6]=(_Float16)f1.z; h[7]=(_Float16)f1.w;
  *(half8*)(g_half + i) = h;
}

// --- main: 30-step RVQ, CODEBOOK-SPLIT wave pairs.
// 512 blocks x 4 waves = 2048 waves -> 8 waves/CU = 2/SIMD (if 256-VGPR waves
// pair up in the 512/lane unified pool — this round's decisive experiment).
// Wave pair (p = wv>>1) shares the same 32 t-rows; member h = wv&1 scores
// codebook half h (codes h*512 .. h*512+511, 16 groups). Top-2 lists merge in
// LDS (64 entries/row); both waves redundantly scan + fp64-rescore + update
// identical rmast copies (zero cross-wave register state, R0 register shape).
// Inner-loop code is VERBATIM R0 (the only allocation verified clean at the
// 256-VGPR cliff — R6/R7's med3/packing variants flipped to multi-GB scratch).
__global__ __launch_bounds__(256) void rvq_main(
    const float* __restrict__ x, const float* __restrict__ cb,
    const float* __restrict__ sumsq, double* __restrict__ lossAcc,
    float* __restrict__ out)
{
  __shared__ float sCS[2][32][66];   // per-pair merged packed top2 (64 entries + pad)
  __shared__ int   sI4[4][32][4];    // per-wave private top-4 global code ids

  const int tid  = threadIdx.x;
  const int wv   = tid>>6;
  const int ln   = tid&63;
  const int col  = ln&15;
  const int quad = ln>>4;
  const int pr   = wv>>1;            // pair: which 32-row tile
  const int hf   = wv&1;             // codebook half
  const int blk  = blockIdx.x;
  const int b    = blk>>6;
  const int t0   = ((blk&63)<<6) + (pr<<5);

  // residual fp64, A-frag distribution: row = rt*16+col, dim = kc*32+quad*8+j
  double rmast[2][4][8];
#pragma unroll
  for (int rt=0;rt<2;++rt){
    const int t = t0 + rt*16 + col;
#pragma unroll
    for (int kc=0;kc<4;++kc)
#pragma unroll
      for (int j=0;j<8;++j){
        const int d = kc*32 + quad*8 + j;
        rmast[rt][kc][j] = (double)x[((size_t)b*D_ + d)*T_ + t];
      }
  }

  half8 ah[2][4];
  auto makeAB = [&](){
#pragma unroll
    for (int rt=0;rt<2;++rt)
#pragma unroll
      for (int kc=0;kc<4;++kc){
        half8 h;
#pragma unroll
        for (int j=0;j<8;++j) h[j] = (_Float16)(float)rmast[rt][kc][j];
        ah[rt][kc] = h;
      }
  };
  makeAB();

  double lossd = 0.0;

  // register pipeline buffers: B-fragments + cc for one group (32 codes)
  half8 bufA[8], bufB[8];
  float ccA[2],  ccB[2];

  const size_t hoff = (size_t)hf*512;   // code offset of this wave's half

  auto loadGroup = [&](const _Float16* cbh, const float* ssq, int g, half8* Bv, float* cc){
#pragma unroll
    for (int kc=0;kc<4;++kc)
#pragma unroll
      for (int ct=0;ct<2;++ct){
        const int n = g*32 + ct*16 + col;
        Bv[kc*2+ct] = *(const half8*)(cbh + n*128 + kc*32 + quad*8);
      }
#pragma unroll
    for (int ct=0;ct<2;++ct)
      cc[ct] = ssq[(g*2+ct)*16 + col];
  };

  loadGroup(g_half + hoff*D_, sumsq + hoff, 0, bufA, ccA);   // prologue: q=0, group 0

  for (int q=0;q<Q_;++q){
    const float*    cbq = cb     + (size_t)q*C_*D_;            // full codebook (rescore)
    const _Float16* cbh = g_half + (size_t)q*C_*D_ + hoff*D_;  // this wave's half
    const float*    ssq = sumsq  + q*C_ + hoff;

    // packed top-2 per cell: score float with low 6 mantissa bits = cid (0..31)
    float p1[2][4], p2[2][4];
#pragma unroll
    for (int rt=0;rt<2;++rt)
#pragma unroll
      for (int rg=0;rg<4;++rg){ p1[rt][rg]=3.0e38f; p2[rt][rg]=3.0e38f; }

#pragma unroll
    for (int g=0; g<16; ++g){
      half8* cur = (g&1) ? bufB : bufA;
      float* ccc = (g&1) ? ccB  : ccA;
      // prefetch next group (codebook loads independent of residual —
      // cross-q prefetch of (q+1, group 0) overlaps the q-tail)
      if (g < 15){
        loadGroup(cbh, ssq, g+1, (g&1)?bufA:bufB, (g&1)?ccA:ccB);
      } else if (q+1 < Q_){
        loadGroup(cbh + C_*D_, ssq + C_, 0, (g&1)?bufA:bufB, (g&1)?ccA:ccB);
      }

      float4_ acc[2][2];
#pragma unroll
      for (int a=0;a<2;++a)
#pragma unroll
        for (int c2=0;c2<2;++c2) acc[a][c2] = (float4_){0.f,0.f,0.f,0.f};
#pragma unroll
      for (int kc=0;kc<4;++kc)
#pragma unroll
        for (int rt=0;rt<2;++rt)
#pragma unroll
          for (int ct=0;ct<2;++ct)
            acc[rt][ct] = __builtin_amdgcn_mfma_f32_16x16x32_f16(ah[rt][kc], cur[kc*2+ct], acc[rt][ct], 0,0,0);

#pragma unroll
      for (int ct=0;ct<2;++ct){
        const int cid = g*2 + ct;                  // code-in-half = cid*16+col
#pragma unroll
        for (int rt=0;rt<2;++rt)
#pragma unroll
          for (int rg=0;rg<4;++rg){
            float sc = fmaf(-2.0f, acc[rt][ct][rg], ccc[ct]);
            unsigned u = (__builtin_bit_cast(unsigned, sc) & ~63u) | (unsigned)cid;
            float sp = __builtin_bit_cast(float, u);
            if (sp < p1[rt][rg]) { p2[rt][rg]=p1[rt][rg]; p1[rt][rg]=sp; }
            else if (sp < p2[rt][rg]) { p2[rt][rg]=sp; }
          }
      }
    }

    // ---- publish per-lane packed top-2 into the pair's merged list ----
#pragma unroll
    for (int rt=0;rt<2;++rt)
#pragma unroll
      for (int rg=0;rg<4;++rg){
        const int row = rt*16 + quad*4 + rg;
        sCS[pr][row][hf*32 + col*2 + 0] = p1[rt][rg];
        sCS[pr][row][hf*32 + col*2 + 1] = p2[rt][rg];
      }

    __syncthreads();   // both halves' top-2 visible

    // ---- lanes 0..31: scan own row's 64 merged entries -> top-4 ids ----
    // (both waves of the pair do this redundantly into private sI4 slots —
    //  removes any cross-wave dependency after this point)
    if (ln < 32){
      const int row = ln;
      float b0=3.0e38f,b1=3.0e38f,b2=3.0e38f,b3=3.0e38f;
      int   e0=0,e1=0,e2=0,e3=0;
#pragma unroll
      for (int c2=0;c2<64;++c2){
        const float sc = sCS[pr][row][c2];
        const int   id = ((c2>>5)<<9) + (int)((__builtin_bit_cast(unsigned, sc) & 63u)<<4) + ((c2&31)>>1);
        const bool l0 = (sc<b0);
        const bool l1 = (sc<b1);
        const bool l2 = (sc<b2);
        const bool l3 = (sc<b3);
        if (l3){
          b3 = l2 ? b2 : sc;  e3 = l2 ? e2 : id;
          if (l2){
            b2 = l1 ? b1 : sc;  e2 = l1 ? e1 : id;
            if (l1){
              b1 = l0 ? b0 : sc;  e1 = l0 ? e0 : id;
              if (l0){ b0 = sc; e0 = id; }
            }
          }
        }
      }
      sI4[wv][row][0]=e0; sI4[wv][row][1]=e1; sI4[wv][row][2]=e2; sI4[wv][row][3]=e3;
    }

    __syncthreads();   // all scans done before sCS is overwritten next q

    // ---- fp64 exact rescore of top-4, winner update (verbatim R0) ----------
#pragma unroll
    for (int rt=0;rt<2;++rt){
      const int m = rt*16 + col;
      double bestS = 1.0e300; int bestJ = 0x7fffffff;
#pragma unroll
      for (int cnd=0;cnd<4;++cnd){
        const int jj = sI4[wv][m][cnd];
        const float* p = cbq + ((size_t)jj<<7) + (quad<<3);
        double sd = 0.0;
#pragma unroll
        for (int kc=0;kc<4;++kc){
          float4_ a0 = *(const float4_*)(p + kc*32);
          float4_ a1 = *(const float4_*)(p + kc*32 + 4);
          float fv[8] = {a0.x,a0.y,a0.z,a0.w,a1.x,a1.y,a1.z,a1.w};
#pragma unroll
          for (int j=0;j<8;++j){
            double cd = (double)fv[j];
            sd += cd*(cd - 2.0*rmast[rt][kc][j]);
          }
        }
        sd += __shfl_xor(sd, 16); sd += __shfl_xor(sd, 32);
        if ((sd < bestS) || (sd == bestS && jj < bestJ)){ bestS = sd; bestJ = jj; }
      }
      const float* pw = cbq + ((size_t)bestJ<<7) + (quad<<3);
#pragma unroll
      for (int kc=0;kc<4;++kc){
        float4_ w0 = *(const float4_*)(pw + kc*32);
        float4_ w1 = *(const float4_*)(pw + kc*32 + 4);
        float fw[8] = {w0.x,w0.y,w0.z,w0.w,w1.x,w1.y,w1.z,w1.w};
#pragma unroll
        for (int j=0;j<8;++j){
          double rn = rmast[rt][kc][j] - (double)fw[j];
          rmast[rt][kc][j] = rn;
          lossd += rn*rn;
        }
      }
    }
    makeAB();
  }

  // ---- epilogue: quantized = x - r_final (half 0 of each pair writes) ----
  if (hf == 0){
#pragma unroll
    for (int rt=0;rt<2;++rt){
      const int t = t0 + rt*16 + col;
#pragma unroll
      for (int kc=0;kc<4;++kc)
#pragma unroll
        for (int j=0;j<8;++j){
          const int d = kc*32 + quad*8 + j;
          const size_t o = ((size_t)b*D_ + d)*T_ + t;
          out[o] = (float)((double)x[o] - rmast[rt][kc][j]);
        }
    }
  }
#pragma unroll
  for (int mk=1; mk<64; mk<<=1) lossd += __shfl_xor(lossd, mk);
  if (ln==0 && hf==0) atomicAdd(lossAcc, lossd);
}

__global__ void rvq_fin(const double* __restrict__ lossAcc, float* __restrict__ out){
  out[(size_t)B_*D_*T_] = (float)(*lossAcc * (1.0/((double)B_*(double)D_*(double)T_)));
}

extern "C" void kernel_launch(void* const* d_in, const int* in_sizes, int n_in,
                              void* d_out, int out_size, void* d_ws, size_t ws_size,
                              hipStream_t stream) {
  const float* x  = (const float*)d_in[0];   // [B, D, T] fp32
  const float* cb = (const float*)d_in[1];   // [Q, C, D] fp32
  float* out      = (float*)d_out;           // [B*D*T] quantized + [1] loss
  double* lossAcc = (double*)d_ws;
  float*  sumsq   = (float*)((char*)d_ws + 256);   // Q*C floats

  hipMemsetAsync(d_ws, 0, 256, stream);
  rvq_prep<<<Q_*C_/128, 256, 0, stream>>>(cb, sumsq);
  rvq_h   <<<(Q_*C_*D_)/(256*8), 256, 0, stream>>>(cb);
  rvq_main<<<(B_*T_)/64, 256, 0, stream>>>(x, cb, sumsq, lossAcc, out);
  rvq_fin <<<1, 1, 0, stream>>>(lossAcc, out);
}